// Round 8
// baseline (128.011 us; speedup 1.0000x reference)
//
#include <hip/hip_runtime.h>
#include <hip/hip_bf16.h>
#include <math.h>

#define HS 64
#define NE 128
#define TSEQ 2048

typedef short s8v __attribute__((ext_vector_type(8)));   // 8 bf16 (4 VGPRs) MFMA A/B frag
typedef float f4v __attribute__((ext_vector_type(4)));   // 4 fp32 MFMA C/D frag

__device__ __forceinline__ float bf2f(unsigned short h) {
    return __uint_as_float(((unsigned int)h) << 16);
}

__device__ __forceinline__ unsigned int pkbf(float a, float b) {
    union { __hip_bfloat162 h; unsigned int u; } cv;
    cv.h = __float22bfloat162_rn(make_float2(a, b));
    return cv.u;
}

__device__ __forceinline__ s8v mk_s8v(unsigned int a, unsigned int b,
                                      unsigned int c, unsigned int d) {
    union { unsigned int u[4]; s8v v; } cv;
    cv.u[0] = a; cv.u[1] = b; cv.u[2] = c; cv.u[3] = d;
    return cv.v;
}

// raw v_exp_f32 (2^x). exp2f without -ffast-math is an OCML call — critical-path killer.
__device__ __forceinline__ float fexp2(float x) {
    float r;
    asm("v_exp_f32 %0, %1" : "=v"(r) : "v"(x));
    return r;
}

// async global->LDS, 16B per lane (dest = wave-uniform base + lane*16).
__device__ __forceinline__ void glds16(const unsigned short* g, unsigned short* l) {
    __builtin_amdgcn_global_load_lds(
        (const __attribute__((address_space(1))) unsigned int*)g,
        (__attribute__((address_space(3))) unsigned int*)l,
        16, 0, 0);
}

// ---------------- QKV projection, W converted inline (wconv fused away) ----------
__global__ __launch_bounds__(256) void qkv(
    const float* __restrict__ x,
    const float* __restrict__ Wq, const float* __restrict__ Wk,
    const float* __restrict__ Wv,
    const float* __restrict__ bq, const float* __restrict__ bk,
    const float* __restrict__ bv,
    unsigned short* __restrict__ qo, unsigned short* __restrict__ ko,
    unsigned short* __restrict__ vt)
{
    __shared__ __align__(16) unsigned short Ws[192 * 136];  // 51 KB; reused for transpose

    const int tid = threadIdx.x;
    const int w = tid >> 6;
    const int lane = tid & 63;
    const int quad = lane >> 4;
    const int li = lane & 15;
    const size_t blk0 = (size_t)blockIdx.x * 64;
    const size_t row0w = blk0 + (size_t)w * 16;

    // W -> bf16 LDS, transposed [mat*64+n][k], q pre-scaled by 64^-0.5*log2(e).
    // W is [128][64] row-major: W[k][n] at k*64+n; dest row ng covers k=c*8..+8.
#pragma unroll
    for (int p = 0; p < 12; ++p) {
        const int idx = p * 256 + tid;
        const int ng = idx >> 4;        // 0..191
        const int c = idx & 15;
        const float* Wsrc = (ng < 64) ? Wq : (ng < 128) ? Wk : Wv;
        const float s = (ng < 64) ? 0.18033688f : 1.0f;
        const float* wp = Wsrc + c * 8 * 64 + (ng & 63);
        unsigned int u0 = pkbf(wp[0] * s,   wp[64] * s);
        unsigned int u1 = pkbf(wp[128] * s, wp[192] * s);
        unsigned int u2 = pkbf(wp[256] * s, wp[320] * s);
        unsigned int u3 = pkbf(wp[384] * s, wp[448] * s);
        *(s8v*)&Ws[ng * 136 + c * 8] = mk_s8v(u0, u1, u2, u3);
    }

    s8v a[4];
    const float* xr = x + (row0w + li) * NE + quad * 8;
#pragma unroll
    for (int ks = 0; ks < 4; ++ks) {
        float4 f0 = *(const float4*)(xr + ks * 32);
        float4 f1 = *(const float4*)(xr + ks * 32 + 4);
        a[ks] = mk_s8v(pkbf(f0.x, f0.y), pkbf(f0.z, f0.w),
                       pkbf(f1.x, f1.y), pkbf(f1.z, f1.w));
    }

    __syncthreads();

    f4v acc[12];
#pragma unroll
    for (int nt = 0; nt < 12; ++nt) acc[nt] = (f4v){0.f, 0.f, 0.f, 0.f};

#pragma unroll
    for (int nt = 0; nt < 12; ++nt) {
        const unsigned short* wr = &Ws[(nt * 16 + li) * 136 + quad * 8];
#pragma unroll
        for (int ks = 0; ks < 4; ++ks) {
            s8v bfr = *(const s8v*)(wr + ks * 32);
            acc[nt] = __builtin_amdgcn_mfma_f32_16x16x32_bf16(a[ks], bfr, acc[nt], 0, 0, 0);
        }
    }

    const size_t bidx = row0w >> 11;
    const size_t trow0 = row0w & 2047;
#pragma unroll
    for (int nt = 0; nt < 4; ++nt) {
        const float bias = bv[nt * 16 + li];
        unsigned int lo = pkbf(acc[nt + 8][0] + bias, acc[nt + 8][1] + bias);
        unsigned int hi = pkbf(acc[nt + 8][2] + bias, acc[nt + 8][3] + bias);
        *(uint2*)(vt + (bidx * HS + nt * 16 + li) * TSEQ + trow0 + quad * 4) =
            make_uint2(lo, hi);
    }

    __syncthreads();

    float* Qt = (float*)Ws;            // [64][68]
    float* Kt = Qt + 64 * 68;
    const float sq = 0.18033688f;
    const int lrow0 = w * 16 + quad * 4;
#pragma unroll
    for (int nt = 0; nt < 4; ++nt) {
        const int col = nt * 16 + li;
        const float bq_ = bq[col] * sq;
        const float bk_ = bk[col];
#pragma unroll
        for (int r = 0; r < 4; ++r) {
            Qt[(lrow0 + r) * 68 + col] = acc[nt][r] + bq_;
            Kt[(lrow0 + r) * 68 + col] = acc[nt + 4][r] + bk_;
        }
    }

    __syncthreads();

    const int row = tid >> 2;
    const int seg = tid & 3;
    {
        const float* src = &Qt[row * 68 + seg * 16];
        float4 f0 = *(const float4*)src;
        float4 f1 = *(const float4*)(src + 4);
        float4 f2 = *(const float4*)(src + 8);
        float4 f3 = *(const float4*)(src + 12);
        s8v d0 = mk_s8v(pkbf(f0.x, f0.y), pkbf(f0.z, f0.w), pkbf(f1.x, f1.y), pkbf(f1.z, f1.w));
        s8v d1 = mk_s8v(pkbf(f2.x, f2.y), pkbf(f2.z, f2.w), pkbf(f3.x, f3.y), pkbf(f3.z, f3.w));
        unsigned short* dst = qo + (blk0 + row) * HS + seg * 16;
        *(s8v*)dst = d0;
        *(s8v*)(dst + 8) = d1;
    }
    {
        const float* src = &Kt[row * 68 + seg * 16];
        float4 f0 = *(const float4*)src;
        float4 f1 = *(const float4*)(src + 4);
        float4 f2 = *(const float4*)(src + 8);
        float4 f3 = *(const float4*)(src + 12);
        s8v d0 = mk_s8v(pkbf(f0.x, f0.y), pkbf(f0.z, f0.w), pkbf(f1.x, f1.y), pkbf(f1.z, f1.w));
        s8v d1 = mk_s8v(pkbf(f2.x, f2.y), pkbf(f2.z, f2.w), pkbf(f3.x, f3.y), pkbf(f3.z, f3.w));
        unsigned short* dst = ko + (blk0 + row) * HS + seg * 16;
        *(s8v*)dst = d0;
        *(s8v*)(dst + 8) = d1;
    }
}

// ---------------- Flash attention: Q128 x K64, SINGLE-buffered K/V ----------------
// LDS 40.5 -> 24 KB: blocks/CU cap 3 -> 6; with the 1152-block grid residency
// rises 3 -> 4.5 blocks/CU (12 -> 18 waves). Staging latency is exposed once
// per iteration but hidden by cross-block TLP (the extra resident blocks).
// Classic race-free 2-barrier loop; compute core identical to R7's proven one.
__device__ __forceinline__ void attn_tile_group(
    const unsigned short* Kc, const unsigned short* Vc,
    char* pbse, int lane, int quad, int li, int swz0, int swz1,
    int tl, int dg, int qrow, s8v qf0, s8v qf1, f4v* c_o, float& lsum)
{
    float pr[4][4];
    float rs = 0.f;
#pragma unroll
    for (int kt = 0; kt < 4; ++kt) {
        const unsigned short* krow = Kc + (kt * 16 + li) * 64;
        s8v k0 = *(const s8v*)(krow + swz0);
        s8v k1 = *(const s8v*)(krow + swz1);
        f4v cst = (f4v){0.f, 0.f, 0.f, 0.f};
        __builtin_amdgcn_s_setprio(1);
        cst = __builtin_amdgcn_mfma_f32_16x16x32_bf16(k0, qf0, cst, 0, 0, 0);
        cst = __builtin_amdgcn_mfma_f32_16x16x32_bf16(k1, qf1, cst, 0, 0, 0);
        __builtin_amdgcn_s_setprio(0);
        if (tl == dg) {
            const int key0 = (tl << 6) + kt * 16 + quad * 4;
#pragma unroll
            for (int rr = 0; rr < 4; ++rr)
                if (key0 + rr > qrow) cst[rr] = -INFINITY;
        }
#pragma unroll
        for (int rr = 0; rr < 4; ++rr) {
            pr[kt][rr] = fexp2(cst[rr]);
            rs += pr[kt][rr];
        }
    }
    lsum += rs;

    // P -> LDS (granule-transposed, conflict-free; wave-private buffer)
#pragma unroll
    for (int kt = 0; kt < 4; ++kt) {
        *(uint2*)(pbse + (kt * 2 + (quad >> 1)) * 256 + li * 16 + (quad & 1) * 8) =
            make_uint2(pkbf(pr[kt][0], pr[kt][1]), pkbf(pr[kt][2], pr[kt][3]));
    }
    s8v pf0 = *(const s8v*)(pbse + lane * 16);
    s8v pf1 = *(const s8v*)(pbse + 1024 + lane * 16);

    // O^T += V^T . P^T
#pragma unroll
    for (int f = 0; f < 4; ++f) {
        const unsigned short* vrow = Vc + (f * 16 + li) * 64;
        s8v v0 = *(const s8v*)(vrow + swz0);
        s8v v1 = *(const s8v*)(vrow + swz1);
        __builtin_amdgcn_s_setprio(1);
        c_o[f] = __builtin_amdgcn_mfma_f32_16x16x32_bf16(v0, pf0, c_o[f], 0, 0, 0);
        c_o[f] = __builtin_amdgcn_mfma_f32_16x16x32_bf16(v1, pf1, c_o[f], 0, 0, 0);
        __builtin_amdgcn_s_setprio(0);
    }
}

__global__ __launch_bounds__(256, 4) void attn_main(
    const unsigned short* __restrict__ qbf,
    const unsigned short* __restrict__ kb,
    const unsigned short* __restrict__ vtb,
    float* __restrict__ out, unsigned short* __restrict__ pbf,
    float* __restrict__ lsbuf)
{
    __shared__ unsigned short Ks[64 * 64];                 // 8 KB
    __shared__ unsigned short Vs[64 * 64];                 // 8 KB
    __shared__ __align__(16) unsigned short Ps[4][1024];   // 8 KB, per-wave

    const int tid = threadIdx.x;
    const int w = tid >> 6;
    const int lane = tid & 63;
    const int quad = lane >> 4;
    const int li = lane & 15;

    // XCD swizzle: 2 whole batches per XCD (144 blocks/XCD = 2 x 72 chunks).
    const int id = blockIdx.x;
    const int xcd = id & 7;
    const int j = id >> 3;                 // 0..143 within XCD
    const int b = xcd * 2 + (j >= 72);
    const int jj = (j >= 72) ? j - 72 : j;
    const int u = 71 - jj;                 // big chunks dispatched first

    // u -> (qb, c): q-block qb (0..15) has ntile=2qb+2 key-tiles, split into
    // m+1 chunks of <=4 where m=qb>>1. Pair-group m starts at u=m(m+1).
    int m = 0;
    while ((m + 1) * (m + 2) <= u) ++m;    // m<=7
    const int rem = u - m * (m + 1);
    const int qb = 2 * m + (rem > m ? 1 : 0);
    const int c = (rem > m) ? rem - (m + 1) : rem;
    const int nc = m + 1;                  // chunks for this qb
    const int tb = c * 4;
    const int ntile = 2 * qb + 2;
    const int te = (tb + 4 < ntile) ? tb + 4 : ntile;

    const size_t base = (size_t)b * TSEQ;
    const int t0 = qb << 7;
    const int qrow0 = t0 + w * 16 + li;        // group A: rows 0..63 of block
    const int qrow1 = qrow0 + 64;              // group B: rows 64..127
    const int d0 = 2 * qb;                     // diag key-tile for group A
    const int d1 = 2 * qb + 1;                 // diag key-tile for group B

    // Q B-frags for both groups (scale*log2e pre-folded)
    const unsigned short* qrp0 = qbf + (base + qrow0) * HS + quad * 8;
    s8v qA0 = *(const s8v*)qrp0;
    s8v qA1 = *(const s8v*)(qrp0 + 32);
    const unsigned short* qrp1 = qrp0 + 64 * HS;
    s8v qB0 = *(const s8v*)qrp1;
    s8v qB1 = *(const s8v*)(qrp1 + 32);

    // staging geometry (verified): wave w stages K/V rows [w*8,w*8+8) and +32
    const int rA = w * 8 + (lane >> 3);
    const int csw = (lane & 7) ^ (rA & 7);
    const unsigned short* kgA = kb + (base + rA) * HS + csw * 8;
    const unsigned short* kgB = kgA + 32 * HS;
    const unsigned short* vgA = vtb + ((size_t)b * HS + rA) * TSEQ + csw * 8;
    const unsigned short* vgB = vgA + 32 * TSEQ;
    const int ldsA = w * 512 + lane * 8;
    const int ldsB = 2048 + w * 512 + lane * 8;

    // prologue: stage tile tb
    glds16(kgA + (size_t)tb * 4096, &Ks[ldsA]);
    glds16(kgB + (size_t)tb * 4096, &Ks[ldsB]);
    glds16(vgA + (size_t)tb * 64,   &Vs[ldsA]);
    glds16(vgB + (size_t)tb * 64,   &Vs[ldsB]);

    f4v c_oA[4], c_oB[4];
#pragma unroll
    for (int f = 0; f < 4; ++f) {
        c_oA[f] = (f4v){0.f, 0.f, 0.f, 0.f};
        c_oB[f] = (f4v){0.f, 0.f, 0.f, 0.f};
    }
    float lsA = 0.f, lsB = 0.f;

    char* pbse = (char*)&Ps[w][0];
    const int swz0 = (quad ^ (li & 7)) * 8;
    const int swz1 = ((4 + quad) ^ (li & 7)) * 8;

    __syncthreads();   // staged data drained + all waves ready

    for (int tl = tb; tl < te; ++tl) {
        // group A (skip tiles entirely above its diagonal — block-uniform)
        if (tl <= d0)
            attn_tile_group(Ks, Vs, pbse, lane, quad, li, swz0, swz1,
                            tl, d0, qrow0, qA0, qA1, c_oA, lsA);
        // group B (always in range: tl <= 2qb+1 = d1)
        attn_tile_group(Ks, Vs, pbse, lane, quad, li, swz0, swz1,
                        tl, d1, qrow1, qB0, qB1, c_oB, lsB);

        __syncthreads();   // all waves done reading buf before overwrite

        if (tl + 1 < te) {
            glds16(kgA + (size_t)(tl + 1) * 4096, &Ks[ldsA]);
            glds16(kgB + (size_t)(tl + 1) * 4096, &Ks[ldsB]);
            glds16(vgA + (size_t)(tl + 1) * 64,   &Vs[ldsA]);
            glds16(vgB + (size_t)(tl + 1) * 64,   &Vs[ldsB]);
            __syncthreads();   // staged data drained (implicit vmcnt(0))
        }
    }

    // per-row lsum (sum the 4 quads)
    lsA += __shfl_xor(lsA, 16);
    lsA += __shfl_xor(lsA, 32);
    lsB += __shfl_xor(lsB, 16);
    lsB += __shfl_xor(lsB, 32);

    if (nc == 1) {
        const float invA = 1.0f / lsA;
        float* orowA = out + (base + qrow0) * HS + quad * 4;
#pragma unroll
        for (int f = 0; f < 4; ++f) {
            f4v res = c_oA[f];
            res[0] *= invA; res[1] *= invA; res[2] *= invA; res[3] *= invA;
            *(f4v*)(orowA + f * 16) = res;
        }
        const float invB = 1.0f / lsB;
        float* orowB = out + (base + qrow1) * HS + quad * 4;
#pragma unroll
        for (int f = 0; f < 4; ++f) {
            f4v res = c_oB[f];
            res[0] *= invB; res[1] *= invB; res[2] *= invB; res[3] *= invB;
            *(f4v*)(orowB + f * 16) = res;
        }
    } else {
        // bf16 partials [128][64] at pidx = b*70 + (u-2)  (u>=2 iff nc>=2)
        const int pidx = b * 70 + (u - 2);
        unsigned short* pc = pbf + (size_t)pidx * 8192 + (w * 16 + li) * 64;
#pragma unroll
        for (int f = 0; f < 4; ++f) {
            *(uint2*)(pc + f * 16 + quad * 4) =
                make_uint2(pkbf(c_oA[f][0], c_oA[f][1]), pkbf(c_oA[f][2], c_oA[f][3]));
        }
        unsigned short* pc1 = pc + 64 * 64;
#pragma unroll
        for (int f = 0; f < 4; ++f) {
            *(uint2*)(pc1 + f * 16 + quad * 4) =
                make_uint2(pkbf(c_oB[f][0], c_oB[f][1]), pkbf(c_oB[f][2], c_oB[f][3]));
        }
        if (quad == 0) {
            lsbuf[(size_t)pidx * 128 + w * 16 + li] = lsA;
            lsbuf[(size_t)pidx * 128 + 64 + w * 16 + li] = lsB;
        }
    }
}

// ---------------- Partial combine + normalize (qb >= 2) ----------------
__global__ __launch_bounds__(256) void attn_reduce(
    const unsigned short* __restrict__ pbf, const float* __restrict__ lsbuf,
    float* __restrict__ out)
{
    const int g = blockIdx.x;            // 448 = 16 batches * 14 qblocks * 2 halves
    const int b = g / 28;
    const int rem = g - b * 28;
    const int r = 2 + (rem >> 1);        // qb = 2..15
    const int half = rem & 1;
    const int m = r >> 1;
    const int nc = m + 1;
    const int pidx0 = b * 70 + m * (m + 1) + (r & 1) * (m + 1) - 2;

    const int tid = threadIdx.x;
    const int row = half * 64 + (tid >> 2);  // 0..127
    const int seg = tid & 3;                 // 16-col quarter of the 64-wide row

    float acc[16];
#pragma unroll
    for (int k = 0; k < 16; ++k) acc[k] = 0.f;
    float ls = 0.f;

    for (int cc = 0; cc < nc; ++cc) {
        const unsigned short* ps = pbf + (size_t)(pidx0 + cc) * 8192 + row * 64 + seg * 16;
        s8v v0 = *(const s8v*)ps;
        s8v v1 = *(const s8v*)(ps + 8);
#pragma unroll
        for (int e = 0; e < 8; ++e) {
            acc[e] += bf2f((unsigned short)v0[e]);
            acc[8 + e] += bf2f((unsigned short)v1[e]);
        }
        ls += lsbuf[(size_t)(pidx0 + cc) * 128 + row];
    }
    const float inv = 1.0f / ls;
    float* orow = out + ((size_t)b * TSEQ + (r << 7) + row) * HS + seg * 16;
#pragma unroll
    for (int jj = 0; jj < 4; ++jj) {
        *(float4*)(orow + jj * 4) = make_float4(acc[jj * 4] * inv,
                                                acc[jj * 4 + 1] * inv,
                                                acc[jj * 4 + 2] * inv,
                                                acc[jj * 4 + 3] * inv);
    }
}

extern "C" void kernel_launch(void* const* d_in, const int* in_sizes, int n_in,
                              void* d_out, int out_size, void* d_ws, size_t ws_size,
                              hipStream_t stream) {
    const float* x  = (const float*)d_in[0];
    const float* Wk = (const float*)d_in[1];
    const float* bk = (const float*)d_in[2];
    const float* Wq = (const float*)d_in[3];
    const float* bq = (const float*)d_in[4];
    const float* Wv = (const float*)d_in[5];
    const float* bv = (const float*)d_in[6];
    float* outp = (float*)d_out;

    const size_t elems = (size_t)16 * TSEQ * HS;  // 2M per tensor
    unsigned short* qbuf = (unsigned short*)d_ws;
    unsigned short* kbuf = qbuf + elems;
    unsigned short* vbuf = kbuf + elems;          // transposed [b][dim][t]
    unsigned short* pbf  = vbuf + elems;          // [1120][128][64] bf16 partials
    float* lsbuf = (float*)(pbf + (size_t)1120 * 8192);  // [1120][128] lsums

    qkv<<<512, 256, 0, stream>>>(x, Wq, Wk, Wv, bq, bk, bv, qbuf, kbuf, vbuf);
    attn_main<<<1152, 256, 0, stream>>>(qbuf, kbuf, vbuf, outp, pbf, lsbuf);
    attn_reduce<<<448, 256, 0, stream>>>(pbf, lsbuf, outp);
}

// Round 11
// 110.301 us; speedup vs baseline: 1.1606x; 1.1606x over previous
//
#include <hip/hip_runtime.h>
#include <hip/hip_bf16.h>
#include <math.h>

#define HS 64
#define NE 128
#define TSEQ 2048

typedef short s8v __attribute__((ext_vector_type(8)));   // 8 bf16 (4 VGPRs) MFMA A/B frag
typedef float f4v __attribute__((ext_vector_type(4)));   // 4 fp32 MFMA C/D frag

__device__ __forceinline__ unsigned short f2bf(float f) {
    unsigned int u = __float_as_uint(f);
    u += 0x7FFFu + ((u >> 16) & 1u);   // RNE (no NaN inputs here)
    return (unsigned short)(u >> 16);
}

__device__ __forceinline__ float bf2f(unsigned short h) {
    return __uint_as_float(((unsigned int)h) << 16);
}

__device__ __forceinline__ unsigned int pkbf(float a, float b) {
    union { __hip_bfloat162 h; unsigned int u; } cv;
    cv.h = __float22bfloat162_rn(make_float2(a, b));
    return cv.u;
}

__device__ __forceinline__ s8v mk_s8v(unsigned int a, unsigned int b,
                                      unsigned int c, unsigned int d) {
    union { unsigned int u[4]; s8v v; } cv;
    cv.u[0] = a; cv.u[1] = b; cv.u[2] = c; cv.u[3] = d;
    return cv.v;
}

// raw v_exp_f32 (2^x). exp2f without -ffast-math is an OCML call — critical-path killer.
__device__ __forceinline__ float fexp2(float x) {
    float r;
    asm("v_exp_f32 %0, %1" : "=v"(r) : "v"(x));
    return r;
}

// async global->LDS, 16B per lane (dest = wave-uniform base + lane*16).
__device__ __forceinline__ void glds16(const unsigned short* g, unsigned short* l) {
    __builtin_amdgcn_global_load_lds(
        (const __attribute__((address_space(1))) unsigned int*)g,
        (__attribute__((address_space(3))) unsigned int*)l,
        16, 0, 0);
}

// ---------------- W -> bf16, transposed wt[mat][n][k], q pre-scaled ----------------
__global__ __launch_bounds__(256) void wconv(
    const float* __restrict__ Wq, const float* __restrict__ Wk,
    const float* __restrict__ Wv, unsigned short* __restrict__ wt)
{
    const int o0 = (blockIdx.x * 256 + threadIdx.x) * 2;   // 24576 elems total
    const int mat = o0 >> 13;
    const int n = (o0 >> 7) & 63;
    const int k = o0 & 127;        // even
    const float* W = (mat == 0) ? Wq : (mat == 1) ? Wk : Wv;
    const float s = (mat == 0) ? 0.18033688f : 1.0f;   // 64^-0.5 * log2(e)
    unsigned int lo = f2bf(W[k * HS + n] * s);
    unsigned int hi = f2bf(W[(k + 1) * HS + n] * s);
    *(unsigned int*)(wt + o0) = lo | (hi << 16);
}

// ---------------- QKV projection (R1/R7-proven: bf16 MFMA, W staged in LDS) -------
__global__ __launch_bounds__(256) void qkv(
    const float* __restrict__ x, const unsigned short* __restrict__ wt,
    const float* __restrict__ bq, const float* __restrict__ bk,
    const float* __restrict__ bv,
    unsigned short* __restrict__ qo, unsigned short* __restrict__ ko,
    unsigned short* __restrict__ vt)
{
    __shared__ __align__(16) unsigned short Ws[192 * 136];  // 51 KB; reused for transpose

    const int tid = threadIdx.x;
    const int w = tid >> 6;
    const int lane = tid & 63;
    const int quad = lane >> 4;
    const int li = lane & 15;
    const size_t blk0 = (size_t)blockIdx.x * 64;
    const size_t row0w = blk0 + (size_t)w * 16;

#pragma unroll
    for (int p = 0; p < 12; ++p) {
        const int idx = p * 256 + tid;
        const int n = idx >> 4;
        const int c = idx & 15;
        s8v d = *(const s8v*)(wt + idx * 8);
        *(s8v*)&Ws[n * 136 + c * 8] = d;
    }

    s8v a[4];
    const float* xr = x + (row0w + li) * NE + quad * 8;
#pragma unroll
    for (int ks = 0; ks < 4; ++ks) {
        float4 f0 = *(const float4*)(xr + ks * 32);
        float4 f1 = *(const float4*)(xr + ks * 32 + 4);
        a[ks] = mk_s8v(pkbf(f0.x, f0.y), pkbf(f0.z, f0.w),
                       pkbf(f1.x, f1.y), pkbf(f1.z, f1.w));
    }

    __syncthreads();

    f4v acc[12];
#pragma unroll
    for (int nt = 0; nt < 12; ++nt) acc[nt] = (f4v){0.f, 0.f, 0.f, 0.f};

#pragma unroll
    for (int nt = 0; nt < 12; ++nt) {
        const unsigned short* wr = &Ws[(nt * 16 + li) * 136 + quad * 8];
#pragma unroll
        for (int ks = 0; ks < 4; ++ks) {
            s8v bfr = *(const s8v*)(wr + ks * 32);
            acc[nt] = __builtin_amdgcn_mfma_f32_16x16x32_bf16(a[ks], bfr, acc[nt], 0, 0, 0);
        }
    }

    const size_t bidx = row0w >> 11;
    const size_t trow0 = row0w & 2047;
#pragma unroll
    for (int nt = 0; nt < 4; ++nt) {
        const float bias = bv[nt * 16 + li];
        unsigned int lo = pkbf(acc[nt + 8][0] + bias, acc[nt + 8][1] + bias);
        unsigned int hi = pkbf(acc[nt + 8][2] + bias, acc[nt + 8][3] + bias);
        *(uint2*)(vt + (bidx * HS + nt * 16 + li) * TSEQ + trow0 + quad * 4) =
            make_uint2(lo, hi);
    }

    __syncthreads();

    float* Qt = (float*)Ws;            // [64][68]
    float* Kt = Qt + 64 * 68;
    const float sq = 0.18033688f;
    const int lrow0 = w * 16 + quad * 4;
#pragma unroll
    for (int nt = 0; nt < 4; ++nt) {
        const int col = nt * 16 + li;
        const float bq_ = bq[col] * sq;
        const float bk_ = bk[col];
#pragma unroll
        for (int r = 0; r < 4; ++r) {
            Qt[(lrow0 + r) * 68 + col] = acc[nt][r] + bq_;
            Kt[(lrow0 + r) * 68 + col] = acc[nt + 4][r] + bk_;
        }
    }

    __syncthreads();

    const int row = tid >> 2;
    const int seg = tid & 3;
    {
        const float* src = &Qt[row * 68 + seg * 16];
        float4 f0 = *(const float4*)src;
        float4 f1 = *(const float4*)(src + 4);
        float4 f2 = *(const float4*)(src + 8);
        float4 f3 = *(const float4*)(src + 12);
        s8v d0 = mk_s8v(pkbf(f0.x, f0.y), pkbf(f0.z, f0.w), pkbf(f1.x, f1.y), pkbf(f1.z, f1.w));
        s8v d1 = mk_s8v(pkbf(f2.x, f2.y), pkbf(f2.z, f2.w), pkbf(f3.x, f3.y), pkbf(f3.z, f3.w));
        unsigned short* dst = qo + (blk0 + row) * HS + seg * 16;
        *(s8v*)dst = d0;
        *(s8v*)(dst + 8) = d1;
    }
    {
        const float* src = &Kt[row * 68 + seg * 16];
        float4 f0 = *(const float4*)src;
        float4 f1 = *(const float4*)(src + 4);
        float4 f2 = *(const float4*)(src + 8);
        float4 f3 = *(const float4*)(src + 12);
        s8v d0 = mk_s8v(pkbf(f0.x, f0.y), pkbf(f0.z, f0.w), pkbf(f1.x, f1.y), pkbf(f1.z, f1.w));
        s8v d1 = mk_s8v(pkbf(f2.x, f2.y), pkbf(f2.z, f2.w), pkbf(f3.x, f3.y), pkbf(f3.z, f3.w));
        unsigned short* dst = ko + (blk0 + row) * HS + seg * 16;
        *(s8v*)dst = d0;
        *(s8v*)(dst + 8) = d1;
    }
}

// ---------------- Flash attention: Q128 x K64, hybrid staging (robust sync) -------
// K double-buffered (cross-iteration prefetch); V SINGLE-buffered, staged at
// iteration top, consumed after a mid-iteration __syncthreads placed AFTER
// QK-A: its vmcnt(0) drain covers V (and the co-issued K prefetch, ~free by
// then) and the barrier makes all waves' cooperative V stages visible. NO
// counted vmcnt (R9/R10 bug: compiler may reorder independent glds, breaking
// the count). Exposed latency ~ max(0, L2lat - QKA_cover) ~ 0.
// LDS 40.5 -> 32 KB: 3 -> 4 blocks/CU resident (16 waves vs R7's 12).
__device__ __forceinline__ void attn_qk(
    const unsigned short* Kc, char* pbse, int lane, int quad, int li,
    int swz0, int swz1, int tl, int dg, int qrow,
    s8v qf0, s8v qf1, float& lsum, s8v& pf0, s8v& pf1)
{
    float pr[4][4];
    float rs = 0.f;
#pragma unroll
    for (int kt = 0; kt < 4; ++kt) {
        const unsigned short* krow = Kc + (kt * 16 + li) * 64;
        s8v k0 = *(const s8v*)(krow + swz0);
        s8v k1 = *(const s8v*)(krow + swz1);
        f4v cst = (f4v){0.f, 0.f, 0.f, 0.f};
        __builtin_amdgcn_s_setprio(1);
        cst = __builtin_amdgcn_mfma_f32_16x16x32_bf16(k0, qf0, cst, 0, 0, 0);
        cst = __builtin_amdgcn_mfma_f32_16x16x32_bf16(k1, qf1, cst, 0, 0, 0);
        __builtin_amdgcn_s_setprio(0);
        if (tl == dg) {
            const int key0 = (tl << 6) + kt * 16 + quad * 4;
#pragma unroll
            for (int rr = 0; rr < 4; ++rr)
                if (key0 + rr > qrow) cst[rr] = -INFINITY;
        }
#pragma unroll
        for (int rr = 0; rr < 4; ++rr) {
            pr[kt][rr] = fexp2(cst[rr]);
            rs += pr[kt][rr];
        }
    }
    lsum += rs;

    // P -> LDS (granule-transposed, conflict-free; wave-private buffer)
#pragma unroll
    for (int kt = 0; kt < 4; ++kt) {
        *(uint2*)(pbse + (kt * 2 + (quad >> 1)) * 256 + li * 16 + (quad & 1) * 8) =
            make_uint2(pkbf(pr[kt][0], pr[kt][1]), pkbf(pr[kt][2], pr[kt][3]));
    }
    pf0 = *(const s8v*)(pbse + lane * 16);
    pf1 = *(const s8v*)(pbse + 1024 + lane * 16);
}

__device__ __forceinline__ void attn_pv(
    const unsigned short* Vc, int li, int swz0, int swz1,
    s8v pf0, s8v pf1, f4v* c_o)
{
#pragma unroll
    for (int f = 0; f < 4; ++f) {
        const unsigned short* vrow = Vc + (f * 16 + li) * 64;
        s8v v0 = *(const s8v*)(vrow + swz0);
        s8v v1 = *(const s8v*)(vrow + swz1);
        __builtin_amdgcn_s_setprio(1);
        c_o[f] = __builtin_amdgcn_mfma_f32_16x16x32_bf16(v0, pf0, c_o[f], 0, 0, 0);
        c_o[f] = __builtin_amdgcn_mfma_f32_16x16x32_bf16(v1, pf1, c_o[f], 0, 0, 0);
        __builtin_amdgcn_s_setprio(0);
    }
}

__global__ __launch_bounds__(256, 4) void attn_main(
    const unsigned short* __restrict__ qbf,
    const unsigned short* __restrict__ kb,
    const unsigned short* __restrict__ vtb,
    float* __restrict__ out, unsigned short* __restrict__ pbf,
    float* __restrict__ lsbuf)
{
    __shared__ unsigned short Ks[2][64 * 64];              // 16 KB (double)
    __shared__ unsigned short Vs[64 * 64];                 // 8 KB (single)
    __shared__ __align__(16) unsigned short Ps[4][1024];   // 8 KB, per-wave

    const int tid = threadIdx.x;
    const int w = tid >> 6;
    const int lane = tid & 63;
    const int quad = lane >> 4;
    const int li = lane & 15;

    // XCD swizzle: 2 whole batches per XCD (144 blocks/XCD = 2 x 72 chunks).
    const int id = blockIdx.x;
    const int xcd = id & 7;
    const int j = id >> 3;                 // 0..143 within XCD
    const int b = xcd * 2 + (j >= 72);
    const int jj = (j >= 72) ? j - 72 : j;
    const int u = 71 - jj;                 // big chunks dispatched first

    // u -> (qb, c): q-block qb (0..15) has ntile=2qb+2 key-tiles, split into
    // m+1 chunks of <=4 where m=qb>>1. Pair-group m starts at u=m(m+1).
    int m = 0;
    while ((m + 1) * (m + 2) <= u) ++m;    // m<=7
    const int rem = u - m * (m + 1);
    const int qb = 2 * m + (rem > m ? 1 : 0);
    const int c = (rem > m) ? rem - (m + 1) : rem;
    const int nc = m + 1;                  // chunks for this qb
    const int tb = c * 4;
    const int ntile = 2 * qb + 2;
    const int te = (tb + 4 < ntile) ? tb + 4 : ntile;

    const size_t base = (size_t)b * TSEQ;
    const int t0 = qb << 7;
    const int qrow0 = t0 + w * 16 + li;        // group A: rows 0..63 of block
    const int qrow1 = qrow0 + 64;              // group B: rows 64..127
    const int d0 = 2 * qb;                     // diag key-tile for group A
    const int d1 = 2 * qb + 1;                 // diag key-tile for group B

    // Q B-frags for both groups (scale*log2e pre-folded)
    const unsigned short* qrp0 = qbf + (base + qrow0) * HS + quad * 8;
    s8v qA0 = *(const s8v*)qrp0;
    s8v qA1 = *(const s8v*)(qrp0 + 32);
    const unsigned short* qrp1 = qrp0 + 64 * HS;
    s8v qB0 = *(const s8v*)qrp1;
    s8v qB1 = *(const s8v*)(qrp1 + 32);

    // staging geometry (verified): wave w stages K/V rows [w*8,w*8+8) and +32
    const int rA = w * 8 + (lane >> 3);
    const int csw = (lane & 7) ^ (rA & 7);
    const unsigned short* kgA = kb + (base + rA) * HS + csw * 8;
    const unsigned short* kgB = kgA + 32 * HS;
    const unsigned short* vgA = vtb + ((size_t)b * HS + rA) * TSEQ + csw * 8;
    const unsigned short* vgB = vgA + 32 * TSEQ;
    const int ldsA = w * 512 + lane * 8;
    const int ldsB = 2048 + w * 512 + lane * 8;

    // prologue: stage K(tb) -> Ks[0] (V staged in-loop)
    glds16(kgA + (size_t)tb * 4096, &Ks[0][ldsA]);
    glds16(kgB + (size_t)tb * 4096, &Ks[0][ldsB]);

    f4v c_oA[4], c_oB[4];
#pragma unroll
    for (int f = 0; f < 4; ++f) {
        c_oA[f] = (f4v){0.f, 0.f, 0.f, 0.f};
        c_oB[f] = (f4v){0.f, 0.f, 0.f, 0.f};
    }
    float lsA = 0.f, lsB = 0.f;

    char* pbse = (char*)&Ps[w][0];
    const int swz0 = (quad ^ (li & 7)) * 8;
    const int swz1 = ((4 + quad) ^ (li & 7)) * 8;

    __syncthreads();   // prologue K drained + all waves ready

    for (int tl = tb; tl < te; ++tl) {
        const int bi = (tl - tb) & 1;
        // stage V(tl) -> Vs and prefetch K(tl+1) -> Ks[bi^1]
        glds16(vgA + (size_t)tl * 64, &Vs[ldsA]);
        glds16(vgB + (size_t)tl * 64, &Vs[ldsB]);
        if (tl + 1 < te) {
            const int nb = bi ^ 1;
            glds16(kgA + (size_t)(tl + 1) * 4096, &Ks[nb][ldsA]);
            glds16(kgB + (size_t)(tl + 1) * 4096, &Ks[nb][ldsB]);
        }
        const unsigned short* Kc = &Ks[bi][0];
        const bool doA = (tl <= d0);

        s8v pfA0, pfA1, pfB0, pfB1;
        if (doA)
            attn_qk(Kc, pbse, lane, quad, li, swz0, swz1,
                    tl, d0, qrow0, qA0, qA1, lsA, pfA0, pfA1);

        // V staged by ALL waves is now visible: vmcnt(0)+lgkmcnt(0)+barrier.
        // QK-A above (~300cyc) covered the V (and co-issued K) L2 latency.
        __syncthreads();

        if (doA)
            attn_pv(Vs, li, swz0, swz1, pfA0, pfA1, c_oA);

        attn_qk(Kc, pbse, lane, quad, li, swz0, swz1,
                tl, d1, qrow1, qB0, qB1, lsB, pfB0, pfB1);
        attn_pv(Vs, li, swz0, swz1, pfB0, pfB1, c_oB);

        __syncthreads();   // all reads of Ks[bi] & Vs done before overwrite
    }

    // per-row lsum (sum the 4 quads)
    lsA += __shfl_xor(lsA, 16);
    lsA += __shfl_xor(lsA, 32);
    lsB += __shfl_xor(lsB, 16);
    lsB += __shfl_xor(lsB, 32);

    if (nc == 1) {
        const float invA = 1.0f / lsA;
        float* orowA = out + (base + qrow0) * HS + quad * 4;
#pragma unroll
        for (int f = 0; f < 4; ++f) {
            f4v res = c_oA[f];
            res[0] *= invA; res[1] *= invA; res[2] *= invA; res[3] *= invA;
            *(f4v*)(orowA + f * 16) = res;
        }
        const float invB = 1.0f / lsB;
        float* orowB = out + (base + qrow1) * HS + quad * 4;
#pragma unroll
        for (int f = 0; f < 4; ++f) {
            f4v res = c_oB[f];
            res[0] *= invB; res[1] *= invB; res[2] *= invB; res[3] *= invB;
            *(f4v*)(orowB + f * 16) = res;
        }
    } else {
        // bf16 partials [128][64] at pidx = b*70 + (u-2)  (u>=2 iff nc>=2)
        const int pidx = b * 70 + (u - 2);
        unsigned short* pc = pbf + (size_t)pidx * 8192 + (w * 16 + li) * 64;
#pragma unroll
        for (int f = 0; f < 4; ++f) {
            *(uint2*)(pc + f * 16 + quad * 4) =
                make_uint2(pkbf(c_oA[f][0], c_oA[f][1]), pkbf(c_oA[f][2], c_oA[f][3]));
        }
        unsigned short* pc1 = pc + 64 * 64;
#pragma unroll
        for (int f = 0; f < 4; ++f) {
            *(uint2*)(pc1 + f * 16 + quad * 4) =
                make_uint2(pkbf(c_oB[f][0], c_oB[f][1]), pkbf(c_oB[f][2], c_oB[f][3]));
        }
        if (quad == 0) {
            lsbuf[(size_t)pidx * 128 + w * 16 + li] = lsA;
            lsbuf[(size_t)pidx * 128 + 64 + w * 16 + li] = lsB;
        }
    }
}

// ---------------- Partial combine + normalize (qb >= 2) ----------------
__global__ __launch_bounds__(256) void attn_reduce(
    const unsigned short* __restrict__ pbf, const float* __restrict__ lsbuf,
    float* __restrict__ out)
{
    const int g = blockIdx.x;            // 448 = 16 batches * 14 qblocks * 2 halves
    const int b = g / 28;
    const int rem = g - b * 28;
    const int r = 2 + (rem >> 1);        // qb = 2..15
    const int half = rem & 1;
    const int m = r >> 1;
    const int nc = m + 1;
    const int pidx0 = b * 70 + m * (m + 1) + (r & 1) * (m + 1) - 2;

    const int tid = threadIdx.x;
    const int row = half * 64 + (tid >> 2);  // 0..127
    const int seg = tid & 3;                 // 16-col quarter of the 64-wide row

    float acc[16];
#pragma unroll
    for (int k = 0; k < 16; ++k) acc[k] = 0.f;
    float ls = 0.f;

    for (int cc = 0; cc < nc; ++cc) {
        const unsigned short* ps = pbf + (size_t)(pidx0 + cc) * 8192 + row * 64 + seg * 16;
        s8v v0 = *(const s8v*)ps;
        s8v v1 = *(const s8v*)(ps + 8);
#pragma unroll
        for (int e = 0; e < 8; ++e) {
            acc[e] += bf2f((unsigned short)v0[e]);
            acc[8 + e] += bf2f((unsigned short)v1[e]);
        }
        ls += lsbuf[(size_t)(pidx0 + cc) * 128 + row];
    }
    const float inv = 1.0f / ls;
    float* orow = out + ((size_t)b * TSEQ + (r << 7) + row) * HS + seg * 16;
#pragma unroll
    for (int jj = 0; jj < 4; ++jj) {
        *(float4*)(orow + jj * 4) = make_float4(acc[jj * 4] * inv,
                                                acc[jj * 4 + 1] * inv,
                                                acc[jj * 4 + 2] * inv,
                                                acc[jj * 4 + 3] * inv);
    }
}

extern "C" void kernel_launch(void* const* d_in, const int* in_sizes, int n_in,
                              void* d_out, int out_size, void* d_ws, size_t ws_size,
                              hipStream_t stream) {
    const float* x  = (const float*)d_in[0];
    const float* Wk = (const float*)d_in[1];
    const float* bk = (const float*)d_in[2];
    const float* Wq = (const float*)d_in[3];
    const float* bq = (const float*)d_in[4];
    const float* Wv = (const float*)d_in[5];
    const float* bv = (const float*)d_in[6];
    float* outp = (float*)d_out;

    const size_t elems = (size_t)16 * TSEQ * HS;  // 2M per tensor
    unsigned short* qbuf = (unsigned short*)d_ws;
    unsigned short* kbuf = qbuf + elems;
    unsigned short* vbuf = kbuf + elems;          // transposed [b][dim][t]
    unsigned short* wtb  = vbuf + elems;          // [3][64][128] bf16
    unsigned short* pbf  = wtb + 32768;           // [1120][128][64] bf16 partials
    float* lsbuf = (float*)(pbf + (size_t)1120 * 8192);  // [1120][128] lsums

    wconv<<<48, 256, 0, stream>>>(Wq, Wk, Wv, wtb);
    qkv<<<512, 256, 0, stream>>>(x, wtb, bq, bk, bv, qbuf, kbuf, vbuf);
    attn_main<<<1152, 256, 0, stream>>>(qbuf, kbuf, vbuf, outp, pbf, lsbuf);
    attn_reduce<<<448, 256, 0, stream>>>(pbf, lsbuf, outp);
}